// Round 5
// baseline (184.941 us; speedup 1.0000x reference)
//
#include <hip/hip_runtime.h>
#include <hip/hip_cooperative_groups.h>
#include <math.h>

namespace cg = cooperative_groups;

#define H 2048
#define Wd 256
#define DEPTH 1024
#define V 128
#define NB 512
#define NT 256

// ws float layout:
//  [0..2]      : a_push, a_pop, a_noop
//  [4..259]    : stack_in[256]
//  [320..2367] : rnn_in emb part [2048]
//  [4096..20479]: partial gate sums, 4 per (dir,unit), wid = dir*2048+unit
#define WS_A      0
#define WS_SIN    4
#define WS_RNNIN  320
#define WS_G      4096

__device__ __forceinline__ float wave_reduce(float v) {
    #pragma unroll
    for (int off = 32; off; off >>= 1) v += __shfl_xor(v, off, 64);
    return v;
}

__device__ __forceinline__ float sigm(float x) { return 1.f / (1.f + expf(-x)); }

__device__ __forceinline__ float dot4(float4 a, float4 b) {
    return a.x * b.x + a.y * b.y + a.z * b.z + a.w * b.w;
}

__global__ void __launch_bounds__(NT) fused_step(
        const int* __restrict__ inp,
        const float* __restrict__ hidden, const float* __restrict__ cell,
        const float* __restrict__ stack,  const float* __restrict__ emb,
        const float* __restrict__ W_ctrl, const float* __restrict__ b_ctrl,
        const float* __restrict__ W_sin,  const float* __restrict__ b_sin,
        const float* __restrict__ w_ih_f, const float* __restrict__ w_hh_f,
        const float* __restrict__ b_ih_f, const float* __restrict__ b_hh_f,
        const float* __restrict__ w_ih_b, const float* __restrict__ w_hh_b,
        const float* __restrict__ b_ih_b, const float* __restrict__ b_hh_b,
        const float* __restrict__ W_dec,  const float* __restrict__ b_dec,
        float* __restrict__ out, float* __restrict__ ws) {
    cg::grid_group grid = cg::this_grid();
    const int b    = blockIdx.x;
    const int tid  = threadIdx.x;
    const int wave = tid >> 6;
    const int lane = tid & 63;
    const int gwave = b * 4 + wave;          // 0..2047 == unit id
    const int unit  = gwave;

    const float4* hv0 = (const float4*)hidden;       // h_f (512 f4) then h_b
    __shared__ float sdots[3];
    __shared__ float sred[4];

    // ===== Phase A pre-work: controller / stack_in / emb copy =====
    if (b == 0) {
        if (wave < 3) {
            const float4* Wr = (const float4*)(W_ctrl + wave * (2 * H));
            float acc = 0.f;
            #pragma unroll
            for (int k = 0; k < 16; ++k) acc += dot4(Wr[lane + 64 * k], hv0[lane + 64 * k]);
            acc = wave_reduce(acc);
            if (lane == 0) sdots[wave] = acc + b_ctrl[wave];
        }
        __syncthreads();
        if (tid == 0) {
            const float m = fmaxf(sdots[0], fmaxf(sdots[1], sdots[2]));
            const float e0 = expf(sdots[0] - m), e1 = expf(sdots[1] - m), e2 = expf(sdots[2] - m);
            const float s = e0 + e1 + e2;
            ws[WS_A + 0] = e0 / s;   // a_push
            ws[WS_A + 1] = e1 / s;   // a_pop
            ws[WS_A + 2] = e2 / s;   // a_noop
        }
    } else if (b <= 256) {
        const int r = b - 1;
        const float4* Wr = (const float4*)(W_sin + (size_t)r * (2 * H));
        float acc = 0.f;
        #pragma unroll
        for (int k = 0; k < 4; ++k) acc += dot4(Wr[tid + 256 * k], hv0[tid + 256 * k]);
        acc = wave_reduce(acc);
        if (lane == 0) sred[wave] = acc;
        __syncthreads();
        if (tid == 0)
            ws[WS_SIN + r] = tanhf(sred[0] + sred[1] + sred[2] + sred[3] + b_sin[r]);
    } else if (b <= 264) {
        const int j = (b - 257) * 256 + tid;   // 0..2047
        ws[WS_RNNIN + j] = emb[(size_t)inp[0] * H + j];
    }

    // ===== Phase A bulk: w_hh dots (no dependency on pre-work) =====
    #pragma unroll
    for (int u = 0; u < 2; ++u) {
        const int dir = u;
        const float* whh = dir ? w_hh_b : w_hh_f;
        const float4* wh_i = (const float4*)whh + (size_t)unit * 512;
        const float4* wh_f = (const float4*)whh + (size_t)(H + unit) * 512;
        const float4* wh_g = (const float4*)whh + (size_t)(2 * H + unit) * 512;
        const float4* wh_o = (const float4*)whh + (size_t)(3 * H + unit) * 512;
        const float4* hv = (const float4*)(hidden + dir * H);
        float ai = 0.f, af = 0.f, ag = 0.f, ao = 0.f;
        #pragma unroll
        for (int k = 0; k < 8; ++k) {
            const int idx = lane + 64 * k;
            const float4 h4 = hv[idx];
            ai += dot4(wh_i[idx], h4);
            af += dot4(wh_f[idx], h4);
            ag += dot4(wh_g[idx], h4);
            ao += dot4(wh_o[idx], h4);
        }
        ai = wave_reduce(ai); af = wave_reduce(af);
        ag = wave_reduce(ag); ao = wave_reduce(ao);
        if (lane == 0) {
            float* p = ws + WS_G + (size_t)(dir * 2048 + unit) * 4;
            p[0] = ai; p[1] = af; p[2] = ag; p[3] = ao;
        }
    }

    grid.sync();

    // ===== Phase B: w_ih dots + epilogue; stack blend hidden here =====
    const float a_push = ws[WS_A + 0];
    const float a_pop  = ws[WS_A + 1];
    const float a_noop = ws[WS_A + 2];

    // x vector per lane: chunks 0..7 from emb part of rnn_in; chunk 8 is the
    // stack_top float4 blended on the fly.
    const float4* xi = (const float4*)(ws + WS_RNNIN);
    float4 x8;
    {
        const float4 s0 = ((const float4*)stack)[lane];
        const float4 s1 = ((const float4*)(stack + Wd))[lane];
        const float4 si = ((const float4*)(ws + WS_SIN))[lane];
        x8.x = a_noop * s0.x + a_push * si.x + a_pop * s1.x;
        x8.y = a_noop * s0.y + a_push * si.y + a_pop * s1.y;
        x8.z = a_noop * s0.z + a_push * si.z + a_pop * s1.z;
        x8.w = a_noop * s0.w + a_push * si.w + a_pop * s1.w;
    }

    #pragma unroll
    for (int u = 0; u < 2; ++u) {
        const int dir = u;
        const float* wih = dir ? w_ih_b : w_ih_f;
        const float* bih = dir ? b_ih_b : b_ih_f;
        const float* bhh = dir ? b_hh_b : b_hh_f;
        const float4* wi_i = (const float4*)wih + (size_t)unit * 576;
        const float4* wi_f = (const float4*)wih + (size_t)(H + unit) * 576;
        const float4* wi_g = (const float4*)wih + (size_t)(2 * H + unit) * 576;
        const float4* wi_o = (const float4*)wih + (size_t)(3 * H + unit) * 576;
        float ai = 0.f, af = 0.f, ag = 0.f, ao = 0.f;
        #pragma unroll
        for (int k = 0; k < 8; ++k) {
            const int idx = lane + 64 * k;
            const float4 x4 = xi[idx];
            ai += dot4(wi_i[idx], x4);
            af += dot4(wi_f[idx], x4);
            ag += dot4(wi_g[idx], x4);
            ao += dot4(wi_o[idx], x4);
        }
        {
            const int idx = lane + 512;
            ai += dot4(wi_i[idx], x8);
            af += dot4(wi_f[idx], x8);
            ag += dot4(wi_g[idx], x8);
            ao += dot4(wi_o[idx], x8);
        }
        ai = wave_reduce(ai); af = wave_reduce(af);
        ag = wave_reduce(ag); ao = wave_reduce(ao);
        if (lane == 0) {
            const float* p = ws + WS_G + (size_t)(dir * 2048 + unit) * 4;
            const float gi = ai + p[0] + bih[unit]         + bhh[unit];
            const float gf = af + p[1] + bih[H + unit]     + bhh[H + unit];
            const float gg = ag + p[2] + bih[2 * H + unit] + bhh[2 * H + unit];
            const float go = ao + p[3] + bih[3 * H + unit] + bhh[3 * H + unit];
            const float c_old = cell[dir * H + unit];
            const float c2 = sigm(gf) * c_old + sigm(gi) * tanhf(gg);
            const float h2 = sigm(go) * tanhf(c2);
            out[V + dir * H + unit] = h2;            // new_hidden
            out[V + 2 * H + dir * H + unit] = c2;    // new_cell
        }
    }

    // stack blend: block b handles rows b and b+512
    #pragma unroll
    for (int u = 0; u < 2; ++u) {
        const int d = b + u * NB;
        const float cur  = stack[d * Wd + tid];
        const float up   = (d == 0) ? ws[WS_SIN + tid] : stack[(d - 1) * Wd + tid];
        const float down = (d == DEPTH - 1) ? 0.f : stack[(d + 1) * Wd + tid];
        out[V + 4 * H + d * Wd + tid] = a_noop * cur + a_push * up + a_pop * down;
    }

    grid.sync();

    // ===== Phase C: decoder (128 waves) =====
    if (gwave < V) {
        const int r = gwave;
        const float4* Wr = (const float4*)(W_dec + (size_t)r * (2 * H));
        const float4* ho = (const float4*)(out + V);
        float acc = 0.f;
        #pragma unroll
        for (int k = 0; k < 16; ++k) acc += dot4(Wr[lane + 64 * k], ho[lane + 64 * k]);
        acc = wave_reduce(acc);
        if (lane == 0) out[r] = acc + b_dec[r];
    }
}

extern "C" void kernel_launch(void* const* d_in, const int* in_sizes, int n_in,
                              void* d_out, int out_size, void* d_ws, size_t ws_size,
                              hipStream_t stream) {
    const int*   inp    = (const int*)  d_in[0];
    const float* hidden = (const float*)d_in[1];
    const float* cell   = (const float*)d_in[2];
    const float* stack  = (const float*)d_in[3];
    const float* emb    = (const float*)d_in[4];
    const float* W_ctrl = (const float*)d_in[5];
    const float* b_ctrl = (const float*)d_in[6];
    const float* W_sin  = (const float*)d_in[7];
    const float* b_sin  = (const float*)d_in[8];
    const float* w_ih_f = (const float*)d_in[9];
    const float* w_hh_f = (const float*)d_in[10];
    const float* b_ih_f = (const float*)d_in[11];
    const float* b_hh_f = (const float*)d_in[12];
    const float* w_ih_b = (const float*)d_in[13];
    const float* w_hh_b = (const float*)d_in[14];
    const float* b_ih_b = (const float*)d_in[15];
    const float* b_hh_b = (const float*)d_in[16];
    const float* W_dec  = (const float*)d_in[17];
    const float* b_dec  = (const float*)d_in[18];

    float* out = (float*)d_out;
    float* ws  = (float*)d_ws;

    void* args[] = {
        (void*)&inp, (void*)&hidden, (void*)&cell, (void*)&stack, (void*)&emb,
        (void*)&W_ctrl, (void*)&b_ctrl, (void*)&W_sin, (void*)&b_sin,
        (void*)&w_ih_f, (void*)&w_hh_f, (void*)&b_ih_f, (void*)&b_hh_f,
        (void*)&w_ih_b, (void*)&w_hh_b, (void*)&b_ih_b, (void*)&b_hh_b,
        (void*)&W_dec, (void*)&b_dec, (void*)&out, (void*)&ws
    };
    hipLaunchCooperativeKernel((void*)fused_step, dim3(NB), dim3(NT), args, 0, stream);
}

// Round 10
// 57.307 us; speedup vs baseline: 3.2272x; 3.2272x over previous
//
#include <hip/hip_runtime.h>
#include <math.h>

#define H 2048
#define Wd 256
#define DEPTH 1024
#define V 128

// ws float layout:
//  [0..2]     : a_push, a_pop, a_noop
//  [4..259]   : stack_in[256]
//  [512..767] : stack_top[256] (pre-blended new_stack row 0)
#define WS_A    0
#define WS_SIN  4
#define WS_TOP  512

__device__ __forceinline__ float wave_reduce(float v) {
    #pragma unroll
    for (int off = 32; off; off >>= 1) v += __shfl_xor(v, off, 64);
    return v;
}

__device__ __forceinline__ float sigm(float x) { return 1.f / (1.f + expf(-x)); }

__device__ __forceinline__ float dot4(float4 a, float4 b) {
    return a.x * b.x + a.y * b.y + a.z * b.z + a.w * b.w;
}

// Kernel 1: 256 blocks. Block r computes the 3 ctrl dots redundantly
// (12 KB L2-hit reads), softmax locally, its W_sin row -> stack_in[r], and
// the pre-blended stack_top[r]. Block 0 also publishes the alphas.
__global__ void k1_front(const float* __restrict__ hidden,
                         const float* __restrict__ stack,
                         const float* __restrict__ W_ctrl, const float* __restrict__ b_ctrl,
                         const float* __restrict__ W_sin, const float* __restrict__ b_sin,
                         float* __restrict__ ws) {
    const int r = blockIdx.x;           // 0..255
    __shared__ float dots[3];
    __shared__ float red[4];
    const int wave = threadIdx.x >> 6, lane = threadIdx.x & 63;
    const float4* hv = (const float4*)hidden;   // 1024 float4 = h2s

    if (wave < 3) {
        const float4* Wr = (const float4*)(W_ctrl + wave * (2 * H));
        float acc = 0.f;
        #pragma unroll
        for (int k = 0; k < 16; ++k) acc += dot4(Wr[lane + 64 * k], hv[lane + 64 * k]);
        acc = wave_reduce(acc);
        if (lane == 0) dots[wave] = acc + b_ctrl[wave];
    }

    const float4* Ws = (const float4*)(W_sin + (size_t)r * (2 * H));
    float acc = 0.f;
    #pragma unroll
    for (int k = 0; k < 4; ++k) acc += dot4(Ws[threadIdx.x + 256 * k], hv[threadIdx.x + 256 * k]);
    acc = wave_reduce(acc);
    if (lane == 0) red[wave] = acc;
    __syncthreads();

    if (threadIdx.x == 0) {
        const float m = fmaxf(dots[0], fmaxf(dots[1], dots[2]));
        const float e0 = expf(dots[0] - m), e1 = expf(dots[1] - m), e2 = expf(dots[2] - m);
        const float s = e0 + e1 + e2;
        const float a_push = e0 / s, a_pop = e1 / s, a_noop = e2 / s;
        const float sin_r = tanhf(red[0] + red[1] + red[2] + red[3] + b_sin[r]);
        ws[WS_SIN + r] = sin_r;
        ws[WS_TOP + r] = a_noop * stack[r] + a_push * sin_r + a_pop * stack[Wd + r];
        if (r == 0) {
            ws[WS_A + 0] = a_push;
            ws[WS_A + 1] = a_pop;
            ws[WS_A + 2] = a_noop;
        }
    }
}

// Kernel 3: fused LSTM (R4-proven structure). One wave per (dir, unit):
// 4 gate dots sharing x/h loads; x chunks 0..7 read straight from the emb
// row, chunk 8 from the pre-blended ws stack_top; gate nonlinearity in the
// epilogue. Each block additionally blends ONE stack row at the end
// (1024 blocks <-> 1024 rows; R9's 2-rows-per-block was an OOB bug).
__global__ void __launch_bounds__(256) k3_lstm(
        const int* __restrict__ inp,
        const float* __restrict__ emb,
        const float* __restrict__ hidden, const float* __restrict__ cell,
        const float* __restrict__ stack,
        const float* __restrict__ w_ih_f, const float* __restrict__ w_hh_f,
        const float* __restrict__ b_ih_f, const float* __restrict__ b_hh_f,
        const float* __restrict__ w_ih_b, const float* __restrict__ w_hh_b,
        const float* __restrict__ b_ih_b, const float* __restrict__ b_hh_b,
        const float* __restrict__ ws,
        float* __restrict__ out) {
    const int wid = (blockIdx.x * blockDim.x + threadIdx.x) >> 6;  // 0..4095
    const int lane = threadIdx.x & 63;
    const int dir = wid >> 11;          // 0 = fwd, 1 = bwd
    const int unit = wid & (H - 1);     // 0..2047

    const float* wih = dir ? w_ih_b : w_ih_f;
    const float* whh = dir ? w_hh_b : w_hh_f;
    const float* bih = dir ? b_ih_b : b_ih_f;
    const float* bhh = dir ? b_hh_b : b_hh_f;

    const float4* xe = (const float4*)(emb + (size_t)inp[0] * H);  // 512 f4
    const float4* hv = (const float4*)(hidden + dir * H);          // 512 f4

    const float4* wi_i = (const float4*)wih + (size_t)unit * 576;
    const float4* wi_f = (const float4*)wih + (size_t)(H + unit) * 576;
    const float4* wi_g = (const float4*)wih + (size_t)(2 * H + unit) * 576;
    const float4* wi_o = (const float4*)wih + (size_t)(3 * H + unit) * 576;
    const float4* wh_i = (const float4*)whh + (size_t)unit * 512;
    const float4* wh_f = (const float4*)whh + (size_t)(H + unit) * 512;
    const float4* wh_g = (const float4*)whh + (size_t)(2 * H + unit) * 512;
    const float4* wh_o = (const float4*)whh + (size_t)(3 * H + unit) * 512;

    float ai = 0.f, af = 0.f, ag = 0.f, ao = 0.f;
    #pragma unroll
    for (int k = 0; k < 8; ++k) {       // emb part of x (2048 floats)
        const int idx = lane + 64 * k;
        const float4 x4 = xe[idx];
        ai += dot4(wi_i[idx], x4);
        af += dot4(wi_f[idx], x4);
        ag += dot4(wi_g[idx], x4);
        ao += dot4(wi_o[idx], x4);
    }
    {                                    // stack_top part of x (256 floats)
        const int idx = 512 + lane;
        const float4 x8 = ((const float4*)(ws + WS_TOP))[lane];
        ai += dot4(wi_i[idx], x8);
        af += dot4(wi_f[idx], x8);
        ag += dot4(wi_g[idx], x8);
        ao += dot4(wi_o[idx], x8);
    }
    #pragma unroll
    for (int k = 0; k < 8; ++k) {       // h part (2048 floats)
        const int idx = lane + 64 * k;
        const float4 h4 = hv[idx];
        ai += dot4(wh_i[idx], h4);
        af += dot4(wh_f[idx], h4);
        ag += dot4(wh_g[idx], h4);
        ao += dot4(wh_o[idx], h4);
    }

    ai = wave_reduce(ai);
    af = wave_reduce(af);
    ag = wave_reduce(ag);
    ao = wave_reduce(ao);

    if (lane == 0) {
        const float gi = ai + bih[unit]         + bhh[unit];
        const float gf = af + bih[H + unit]     + bhh[H + unit];
        const float gg = ag + bih[2 * H + unit] + bhh[2 * H + unit];
        const float go = ao + bih[3 * H + unit] + bhh[3 * H + unit];
        const float c_old = cell[dir * H + unit];
        const float c2 = sigm(gf) * c_old + sigm(gi) * tanhf(gg);
        const float h2 = sigm(go) * tanhf(c2);
        out[V + dir * H + unit] = h2;               // new_hidden
        out[V + 2 * H + dir * H + unit] = c2;       // new_cell
    }

    // stack blend epilogue: one row per block (1024 blocks <-> 1024 rows).
    const float a_push = ws[WS_A + 0];
    const float a_pop  = ws[WS_A + 1];
    const float a_noop = ws[WS_A + 2];
    const int tid = threadIdx.x;
    {
        const int d = blockIdx.x;
        const float cur  = stack[d * Wd + tid];
        const float up   = (d == 0) ? ws[WS_SIN + tid] : stack[(d - 1) * Wd + tid];
        const float down = (d == DEPTH - 1) ? 0.f : stack[(d + 1) * Wd + tid];
        out[V + 4 * H + d * Wd + tid] = a_noop * cur + a_push * up + a_pop * down;
    }
}

// Kernel 5: decoder only. One wave per logit row.
__global__ void k5_dec(const float* __restrict__ out_h, const float* __restrict__ W_dec,
                       const float* __restrict__ b_dec, float* __restrict__ logits) {
    const int r = (blockIdx.x * blockDim.x + threadIdx.x) >> 6;  // 0..127
    const int lane = threadIdx.x & 63;
    const float4* Wr = (const float4*)(W_dec + (size_t)r * (2 * H));
    const float4* hv = (const float4*)out_h;
    float acc = 0.f;
    #pragma unroll
    for (int k = 0; k < 16; ++k)
        acc += dot4(Wr[lane + 64 * k], hv[lane + 64 * k]);
    acc = wave_reduce(acc);
    if (lane == 0) logits[r] = acc + b_dec[r];
}

extern "C" void kernel_launch(void* const* d_in, const int* in_sizes, int n_in,
                              void* d_out, int out_size, void* d_ws, size_t ws_size,
                              hipStream_t stream) {
    const int*   inp    = (const int*)  d_in[0];
    const float* hidden = (const float*)d_in[1];
    const float* cell   = (const float*)d_in[2];
    const float* stack  = (const float*)d_in[3];
    const float* emb    = (const float*)d_in[4];
    const float* W_ctrl = (const float*)d_in[5];
    const float* b_ctrl = (const float*)d_in[6];
    const float* W_sin  = (const float*)d_in[7];
    const float* b_sin  = (const float*)d_in[8];
    const float* w_ih_f = (const float*)d_in[9];
    const float* w_hh_f = (const float*)d_in[10];
    const float* b_ih_f = (const float*)d_in[11];
    const float* b_hh_f = (const float*)d_in[12];
    const float* w_ih_b = (const float*)d_in[13];
    const float* w_hh_b = (const float*)d_in[14];
    const float* b_ih_b = (const float*)d_in[15];
    const float* b_hh_b = (const float*)d_in[16];
    const float* W_dec  = (const float*)d_in[17];
    const float* b_dec  = (const float*)d_in[18];

    float* out = (float*)d_out;
    float* ws  = (float*)d_ws;

    // K1: ctrl + stack_in + pre-blended stack_top (256 blocks)
    k1_front<<<256, 256, 0, stream>>>(hidden, stack, W_ctrl, b_ctrl, W_sin, b_sin, ws);
    // K3: fused LSTM + stack blend epilogue (1024 blocks, 4096 waves)
    k3_lstm<<<1024, 256, 0, stream>>>(inp, emb, hidden, cell, stack,
                                      w_ih_f, w_hh_f, b_ih_f, b_hh_f,
                                      w_ih_b, w_hh_b, b_ih_b, b_hh_b,
                                      ws, out);
    // K5: decoder (32 blocks)
    k5_dec<<<32, 256, 0, stream>>>(out + V, W_dec, b_dec, out);
}